// Round 1
// 100.863 us; speedup vs baseline: 1.1020x; 1.1020x over previous
//
#include <hip/hip_runtime.h>

#define NQ 16384
#define NB 128
#define NF 64
#define HD 128
#define EPSF 1e-8f
#define BTILE 8
#define NBT (NB / BTILE)   // 16 btiles
#define NFP (NF / 2)       // 32 f-pairs

typedef float f32x2 __attribute__((ext_vector_type(2)));
typedef float f32x4 __attribute__((ext_vector_type(4)));

// Packed-pair table row for one (btile, f-pair): SoA of f32x2 over the 8 b's.
// 320 B contiguous; wave-uniform address -> compiler scalarizes to
// s_load_dwordx16 x5; every packed VOP then has exactly 1 SGPR-pair operand.
struct FP2Row {
    f32x2 x2[BTILE];   // -2*P_real   for (f, f+1)
    f32x2 y2[BTILE];   // -2*P_imag
    f32x2 z2[BTILE];   // |P|^2 + eps
    f32x2 w2[BTILE];   // -softplus(qw)
    f32x2 m2[BTILE];   // magnitude weight
};

// ---------- prep: qvals planes (blocks 0..2047) + table (2048..2079) --------
// qA[fp*NQ + q] = (Qr_2fp, Qr_2fp+1, Qi_2fp, Qi_2fp+1)   <- [fp][q] layout so
// qB[fp*NQ + q] = (B0, B1, |Q|mag0, |Q|mag1)                main loads coalesce
__global__ __launch_bounds__(256) void prep_kernel(
    const float* __restrict__ Q,        // [NQ][HD]
    const float* __restrict__ probes,   // [NB][HD]
    const float* __restrict__ angles,   // [NF]
    const float* __restrict__ qw,       // [NB][NF]
    const float* __restrict__ mw,       // [NB][NF]
    f32x4* __restrict__ qA,             // [NFP][NQ]
    f32x4* __restrict__ qB,             // [NFP][NQ]
    FP2Row* __restrict__ tab) {         // [NBT][NFP]
    __shared__ f32x4 sA[8][NFP + 1];    // +1: dodge bank conflicts
    __shared__ f32x4 sB[8][NFP + 1];
    if (blockIdx.x < 2048) {
        // 8 q per block, half-wave (32 lanes) per q; lane sl owns f-pair sl.
        const int qi = threadIdx.x >> 5;
        const int sl = threadIdx.x & 31;
        const int q  = blockIdx.x * 8 + qi;
        const float2* Q2 = (const float2*)Q;
        float2 a = Q2[q * 64 + sl];        // Qr[2sl], Qr[2sl+1]
        float2 c = Q2[q * 64 + 32 + sl];   // Qi[2sl], Qi[2sl+1]
        float ss = a.x * a.x + a.y * a.y + c.x * c.x + c.y * c.y;
        #pragma unroll
        for (int m = 1; m < 32; m <<= 1) ss += __shfl_xor(ss, m);  // half-wave
        float inv = 1.0f / (sqrtf(ss) + EPSF);
        float Qr0 = a.x * inv, Qr1 = a.y * inv;
        float Qi0 = c.x * inv, Qi1 = c.y * inv;
        float B0 = Qr0 * Qr0 + Qi0 * Qi0;
        float B1 = Qr1 * Qr1 + Qi1 * Qi1;
        f32x4 Av; Av.x = Qr0; Av.y = Qr1; Av.z = Qi0; Av.w = Qi1;
        f32x4 Bv; Bv.x = B0;  Bv.y = B1;
        Bv.z = sqrtf(B0 + EPSF); Bv.w = sqrtf(B1 + EPSF);
        sA[qi][sl] = Av;
        sB[qi][sl] = Bv;
        __syncthreads();
        // transposed write-out: 8 consecutive lanes write 128 B contiguous
        const int sl2 = threadIdx.x >> 3;   // f-pair
        const int qi2 = threadIdx.x & 7;    // q within block
        const int qb  = blockIdx.x * 8;
        qA[sl2 * NQ + qb + qi2] = sA[qi2][sl2];
        qB[sl2 * NQ + qb + qi2] = sB[qi2][sl2];
    } else {
        // table: 1 b per wave, lane = f (scatter stores; 32 blocks, negligible)
        const int b = (blockIdx.x - 2048) * 4 + (threadIdx.x >> 6);
        const int f = threadIdx.x & 63;
        float p0 = probes[b * HD + f];
        float p1 = probes[b * HD + 64 + f];
        float ss = p0 * p0 + p1 * p1;
        #pragma unroll
        for (int m = 1; m < 64; m <<= 1) ss += __shfl_xor(ss, m);
        float inv = 1.0f / (sqrtf(ss) + EPSF);
        float pr = p0 * inv, pi = p1 * inv;
        float ang = angles[f];
        float cc = cosf(ang), sn = sinf(ang);
        float Pr = pr * cc - pi * sn;
        float Pi = pr * sn + pi * cc;
        float x = qw[b * NF + f];
        float sp = (x > 0.0f) ? (x + log1pf(expf(-x))) : log1pf(expf(x));
        FP2Row* r = &tab[(b >> 3) * NFP + (f >> 1)];
        const int h  = f & 1;
        const int bb = b & 7;
        ((float*)&r->x2[bb])[h] = -2.0f * Pr;
        ((float*)&r->y2[bb])[h] = -2.0f * Pi;
        ((float*)&r->z2[bb])[h] = Pr * Pr + Pi * Pi + EPSF;
        ((float*)&r->w2[bb])[h] = -sp;
        ((float*)&r->m2[bb])[h] = mw[b * NF + f];
    }
}

// ---------- main kernel ----------
// lane = q -> qA/qB loads are coalesced 16 B/lane (the old layout strided
// 1 KB/lane and shattered every load into ~64 transactions).
// f-pairs processed with packed fp32 (v_pk_add/fma_f32 from v2f32 IR);
// fmax(t,0) guard replaced by sqrt(|t|) -- fabs folds into the source
// modifier of v_sqrt_f32, and |t| only differs when t~0 by fp cancellation.
__global__ __launch_bounds__(256, 4) void main_kernel(
    const FP2Row* __restrict__ tab,     // [NBT][NFP]
    const f32x4* __restrict__ qA,       // [NFP][NQ]
    const f32x4* __restrict__ qB,       // [NFP][NQ]
    const float* __restrict__ bias,     // [NB]
    float* __restrict__ out) {          // [NQ][NB]
    // XCD-bijective swizzle: all 16 bt-blocks of one q-chunk land on ONE XCD
    // (default round-robin spread them over all 8 L2s -> 4x HBM re-fetch).
    const int p    = blockIdx.x;
    const int xcd  = p & 7;
    const int j    = p >> 3;                 // 0..127 per XCD
    const int qblk = xcd * 8 + (j >> 4);     // 0..63
    const int bt   = j & 15;
    const int q    = qblk * 256 + threadIdx.x;

    const FP2Row* __restrict__ tr = tab + bt * NFP;

    f32x2 acc[BTILE];
    #pragma unroll
    for (int i = 0; i < BTILE; ++i) acc[i] = 0.0f;

    // one-iteration register prefetch of the coalesced q-planes
    f32x4 A = qA[q];            // fp = 0
    f32x4 B = qB[q];
    for (int fp = 0; fp < NFP; ++fp) {
        const int fpn = (fp < NFP - 1) ? fp + 1 : fp;
        f32x4 An = qA[fpn * NQ + q];
        f32x4 Bn = qB[fpn * NQ + q];
        f32x2 qr2 = __builtin_shufflevector(A, A, 0, 1);
        f32x2 qi2 = __builtin_shufflevector(A, A, 2, 3);
        f32x2 qz2 = __builtin_shufflevector(B, B, 0, 1);
        f32x2 qm2 = __builtin_shufflevector(B, B, 2, 3);
        const FP2Row* r = tr + fp;
        #pragma unroll
        for (int bb = 0; bb < BTILE; ++bb) {
            f32x2 t = r->z2[bb] + qz2;                          // v_pk_add_f32
            t = __builtin_elementwise_fma(r->y2[bb], qi2, t);   // v_pk_fma_f32
            t = __builtin_elementwise_fma(r->x2[bb], qr2, t);
            f32x2 d;
            d.x = __builtin_amdgcn_sqrtf(__builtin_fabsf(t.x)); // |t| = src mod
            d.y = __builtin_amdgcn_sqrtf(__builtin_fabsf(t.y));
            acc[bb] = __builtin_elementwise_fma(r->w2[bb], d, acc[bb]);
            acc[bb] = __builtin_elementwise_fma(r->m2[bb], qm2, acc[bb]);
        }
        A = An; B = Bn;
    }

    float o[BTILE];
    #pragma unroll
    for (int bb = 0; bb < BTILE; ++bb)
        o[bb] = acc[bb].x + acc[bb].y + bias[bt * BTILE + bb];
    float* op = out + (size_t)q * NB + bt * BTILE;
    *(float4*)op       = make_float4(o[0], o[1], o[2], o[3]);
    *(float4*)(op + 4) = make_float4(o[4], o[5], o[6], o[7]);
}

extern "C" void kernel_launch(void* const* d_in, const int* in_sizes, int n_in,
                              void* d_out, int out_size, void* d_ws, size_t ws_size,
                              hipStream_t stream) {
    const float* Q      = (const float*)d_in[0];   // [16384][128]
    const float* angles = (const float*)d_in[1];   // [64]
    const float* probes = (const float*)d_in[2];   // [128][128]
    const float* qw     = (const float*)d_in[3];   // [128][64]
    const float* mw     = (const float*)d_in[4];   // [128][64]
    const float* bias   = (const float*)d_in[5];   // [128]
    float* out = (float*)d_out;

    char* ws = (char*)d_ws;
    FP2Row* tab = (FP2Row*)ws;                                   // 160 KB
    f32x4*  qA  = (f32x4*)(ws + NBT * NFP * sizeof(FP2Row));     // 8 MB
    f32x4*  qB  = qA + (size_t)NFP * NQ;                         // 8 MB

    prep_kernel<<<2048 + NB / 4, 256, 0, stream>>>(Q, probes, angles, qw, mw, qA, qB, tab);
    main_kernel<<<(NQ / 256) * NBT, 256, 0, stream>>>(tab, qA, qB, bias, out);
}